// Round 2
// baseline (6428.256 us; speedup 1.0000x reference)
//
#include <hip/hip_runtime.h>
#include <hip/hip_bf16.h>

// CrossGRU: 2-layer GRU (N=2048,T=128,IN=64,H=256) + codebook cross-attn + MLP + normalize.
// Round 2: ALL I/O IS FP32 (reference uses jnp.float32). MFMA GRU with bf16 hi/lo split
// weights (prep kernel) + on-the-fly hi/lo state split; 3-term MFMA product for ~fp32
// accuracy. Fixed B-fragment row (must include lane&15). fp32 epilogue.

#define HH    256
#define TT    128
#define NBATCH 2048
#define INP   64

typedef float f32x4 __attribute__((ext_vector_type(4)));
typedef short bf16x8 __attribute__((ext_vector_type(8)));

__device__ __forceinline__ float bf2f(unsigned short s) {
    unsigned u = ((unsigned)s) << 16;
    float f; __builtin_memcpy(&f, &u, 4); return f;
}
__device__ __forceinline__ unsigned short f2bf(float f) {
    unsigned u; __builtin_memcpy(&u, &f, 4);
    unsigned r = (u + 0x7FFFu + ((u >> 16) & 1u)) >> 16;
    return (unsigned short)r;
}

__device__ __forceinline__ void split8(const float* p, bf16x8& hi, bf16x8& lo) {
    f32x4 a0 = *(const f32x4*)p;
    f32x4 a1 = *(const f32x4*)(p + 4);
#pragma unroll
    for (int j = 0; j < 4; ++j) {
        unsigned short h = f2bf(a0[j]);
        hi[j] = (short)h; lo[j] = (short)f2bf(a0[j] - bf2f(h));
    }
#pragma unroll
    for (int j = 0; j < 4; ++j) {
        unsigned short h = f2bf(a1[j]);
        hi[4 + j] = (short)h; lo[4 + j] = (short)f2bf(a1[j] - bf2f(h));
    }
}

// fp32 -> bf16 hi/lo pair
__global__ void cvt_hilo(const float* __restrict__ src, unsigned short* __restrict__ hi,
                         unsigned short* __restrict__ lo, int n)
{
    int i = blockIdx.x * 256 + threadIdx.x;
    if (i >= n) return;
    float f = src[i];
    unsigned short h = f2bf(f);
    hi[i] = h;
    lo[i] = f2bf(f - bf2f(h));
}

// ---------------- GRU step kernel ----------------
// grid 512 x 256. blocks [0,256): layer0 step=step ; [256,512): layer1 step=step-1.
// block: 64 batch rows (m0) x 32 channels (c0). wave w owns m-tile m0+16w, 8 acc n-tiles:
// acc[0..1]=r, acc[2..3]=z, acc[4..5]=hn (h-path), acc[6..7]=xn (x-path).
// A-frag: A[m=lane&15][k=(lane>>4)*8+j]. B-frag: W[n_base+(lane&15)][k=(lane>>4)*8+j].
// C/D: col=lane&15 (n), row=(lane>>4)*4+reg (m).
struct GruW { const unsigned short *ih_hi, *ih_lo, *hh_hi, *hh_lo; const float *bih, *bhh; };

__global__ __launch_bounds__(256) void gru_step(
    const float* __restrict__ h0r, float* __restrict__ h0w,
    const float* __restrict__ h1r, float* __restrict__ h1w,
    const float* __restrict__ x,
    const unsigned short* __restrict__ Wih0hi, const unsigned short* __restrict__ Wih0lo,
    const unsigned short* __restrict__ Whh0hi, const unsigned short* __restrict__ Whh0lo,
    const float* __restrict__ bih0, const float* __restrict__ bhh0,
    const unsigned short* __restrict__ Wih1hi, const unsigned short* __restrict__ Wih1lo,
    const unsigned short* __restrict__ Whh1hi, const unsigned short* __restrict__ Whh1lo,
    const float* __restrict__ bih1, const float* __restrict__ bhh1,
    int step)
{
    const int layer = blockIdx.x >> 8;
    if (layer == 0 && step >= TT) return;
    if (layer == 1 && step == 0) return;
    const int bid = blockIdx.x & 255;
    const int m0 = (bid >> 3) * 64;
    const int c0 = (bid & 7) * 32;
    const int tid = threadIdx.x;
    const int w = tid >> 6;
    const int lane = tid & 63;
    const int l15 = lane & 15;
    const int q = lane >> 4;
    const int arow = m0 + w * 16 + l15;

    const float* hr = layer ? h1r : h0r;
    float*       hw = layer ? h1w : h0w;
    const unsigned short* Whh_hi = layer ? Whh1hi : Whh0hi;
    const unsigned short* Whh_lo = layer ? Whh1lo : Whh0lo;
    const unsigned short* Wih_hi = layer ? Wih1hi : Wih0hi;
    const unsigned short* Wih_lo = layer ? Wih1lo : Wih0lo;
    const float* bih = layer ? bih1 : bih0;
    const float* bhh = layer ? bhh1 : bhh0;

    // B row index per tile (includes lane offset!)
    int nrow[6];
    nrow[0] = c0 + l15;        nrow[1] = c0 + 16 + l15;
    nrow[2] = 256 + c0 + l15;  nrow[3] = 256 + c0 + 16 + l15;
    nrow[4] = 512 + c0 + l15;  nrow[5] = 512 + c0 + 16 + l15;
    const int dmap[6] = { 0, 1, 2, 3, 6, 7 };

    f32x4 acc[8];
#pragma unroll
    for (int i = 0; i < 8; ++i) acc[i] = (f32x4){0.f, 0.f, 0.f, 0.f};

    // ---- h-path: K=256, A = fp32 h split hi/lo ----
    {
        const float* abase = hr + arow * HH;
#pragma unroll
        for (int k0 = 0; k0 < HH; k0 += 32) {
            const int kk = k0 + q * 8;
            bf16x8 ahi, alo;
            split8(abase + kk, ahi, alo);
#pragma unroll
            for (int t = 0; t < 6; ++t) {
                bf16x8 bhi = *(const bf16x8*)(Whh_hi + nrow[t] * HH + kk);
                bf16x8 blo = *(const bf16x8*)(Whh_lo + nrow[t] * HH + kk);
                acc[t] = __builtin_amdgcn_mfma_f32_16x16x32_bf16(ahi, bhi, acc[t], 0, 0, 0);
                acc[t] = __builtin_amdgcn_mfma_f32_16x16x32_bf16(alo, bhi, acc[t], 0, 0, 0);
                acc[t] = __builtin_amdgcn_mfma_f32_16x16x32_bf16(ahi, blo, acc[t], 0, 0, 0);
            }
        }
    }

    // ---- x-path ----
    if (layer == 0) {
        const float* xb = x + arow * (TT * INP) + step * INP;
#pragma unroll
        for (int k0 = 0; k0 < INP; k0 += 32) {
            const int kk = k0 + q * 8;
            bf16x8 ahi, alo;
            split8(xb + kk, ahi, alo);
#pragma unroll
            for (int t = 0; t < 6; ++t) {
                bf16x8 bhi = *(const bf16x8*)(Wih_hi + nrow[t] * INP + kk);
                bf16x8 blo = *(const bf16x8*)(Wih_lo + nrow[t] * INP + kk);
                acc[dmap[t]] = __builtin_amdgcn_mfma_f32_16x16x32_bf16(ahi, bhi, acc[dmap[t]], 0, 0, 0);
                acc[dmap[t]] = __builtin_amdgcn_mfma_f32_16x16x32_bf16(alo, bhi, acc[dmap[t]], 0, 0, 0);
                acc[dmap[t]] = __builtin_amdgcn_mfma_f32_16x16x32_bf16(ahi, blo, acc[dmap[t]], 0, 0, 0);
            }
        }
    } else {
        // layer1 x-input = h0 state after this step (fp32)
        const float* xb = h0r + arow * HH;
#pragma unroll
        for (int k0 = 0; k0 < HH; k0 += 32) {
            const int kk = k0 + q * 8;
            bf16x8 ahi, alo;
            split8(xb + kk, ahi, alo);
#pragma unroll
            for (int t = 0; t < 6; ++t) {
                bf16x8 bhi = *(const bf16x8*)(Wih_hi + nrow[t] * HH + kk);
                bf16x8 blo = *(const bf16x8*)(Wih_lo + nrow[t] * HH + kk);
                acc[dmap[t]] = __builtin_amdgcn_mfma_f32_16x16x32_bf16(ahi, bhi, acc[dmap[t]], 0, 0, 0);
                acc[dmap[t]] = __builtin_amdgcn_mfma_f32_16x16x32_bf16(alo, bhi, acc[dmap[t]], 0, 0, 0);
                acc[dmap[t]] = __builtin_amdgcn_mfma_f32_16x16x32_bf16(ahi, blo, acc[dmap[t]], 0, 0, 0);
            }
        }
    }

    // ---- gates + state update ----
#pragma unroll
    for (int s = 0; s < 2; ++s) {
        const int col = c0 + s * 16 + l15;
        const float brb = bih[col] + bhh[col];
        const float bzb = bih[256 + col] + bhh[256 + col];
        const float bni = bih[512 + col];
        const float bnh = bhh[512 + col];
        const f32x4 ar = acc[s], az = acc[2 + s], ah = acc[4 + s], ax = acc[6 + s];
#pragma unroll
        for (int rg = 0; rg < 4; ++rg) {
            const int rrow = m0 + w * 16 + q * 4 + rg;
            const float rr = 1.f / (1.f + expf(-(ar[rg] + brb)));
            const float zz = 1.f / (1.f + expf(-(az[rg] + bzb)));
            const float nn = tanhf(ax[rg] + bni + rr * (ah[rg] + bnh));
            const float ho = hr[rrow * HH + col];
            hw[rrow * HH + col] = (1.f - zz) * nn + zz * ho;
        }
    }
}

// ---------------- epilogue kernels (fp32) ----------------

// P[p][h][l][d] = sum_j A[l][j] * W_p[h][j][d] + b_p[h][d]
__global__ void proj3_kernel(const float* __restrict__ A, int M,
    const float* __restrict__ Wk, const float* __restrict__ bk,
    const float* __restrict__ Wv, const float* __restrict__ bv,
    const float* __restrict__ Wq, const float* __restrict__ bq,
    float* __restrict__ ok, float* __restrict__ ov, float* __restrict__ oq, int np)
{
    int idx = blockIdx.x * 256 + threadIdx.x;
    if (idx >= np * 2 * M * 128) return;
    int d = idx & 127;
    int rest = idx >> 7;
    int l = rest % M;
    int ph = rest / M;
    int h = ph & 1, p = ph >> 1;
    const float* W = (p == 0) ? Wk : ((p == 1) ? Wv : Wq);
    const float* b = (p == 0) ? bk : ((p == 1) ? bv : bq);
    float* o = (p == 0) ? ok : ((p == 1) ? ov : oq);
    float accv = b[h * 128 + d];
    const float* a = A + l * 256;
    const float* wp = W + h * (256 * 128) + d;
    for (int j = 0; j < 256; ++j) accv += a[j] * wp[j * 128];
    o[(h * M + l) * 128 + d] = accv;
}

// qhR[h][i][d] = R[i]·Wq[h,:,d] + bq
__global__ void projR_kernel(const float* __restrict__ R,
    const float* __restrict__ Wq, const float* __restrict__ bq,
    float* __restrict__ oq)
{
    int idx = blockIdx.x * 256 + threadIdx.x;
    if (idx >= 2 * 30 * 128) return;
    int d = idx & 127;
    int rest = idx >> 7;
    int l = rest % 30;
    int h = rest / 30;
    float a = bq[h * 128 + d];
    const float* r = R + l * 256;
    const float* wp = Wq + h * 32768 + d;
    for (int j = 0; j < 256; ++j) a += r[j] * wp[j * 128];
    oq[(h * 30 + l) * 128 + d] = a;
}

__global__ void scores1_kernel(const float* __restrict__ qhR, const float* __restrict__ kh,
                               float* __restrict__ s1)
{
    int idx = blockIdx.x * 256 + threadIdx.x;
    if (idx >= 2 * 30 * 2048) return;
    int k = idx & 2047;
    int rest = idx >> 11;
    int i = rest % 30;
    int h = rest / 30;
    const f32x4* qp = (const f32x4*)(qhR + (h * 30 + i) * 128);
    const f32x4* kp = (const f32x4*)(kh + (h * 2048 + k) * 128);
    float acc = 0.f;
    for (int dd = 0; dd < 32; ++dd) {
        f32x4 a = qp[dd], b = kp[dd];
        acc += a[0] * b[0] + a[1] * b[1] + a[2] * b[2] + a[3] * b[3];
    }
    s1[idx] = acc * 0.08838834764831845f;
}

__global__ void softmax1_kernel(float* __restrict__ s1)
{
    __shared__ float red[256];
    float* p = s1 + blockIdx.x * 2048;
    int tid = threadIdx.x;
    float mx = -1e30f;
    for (int k = tid; k < 2048; k += 256) mx = fmaxf(mx, p[k]);
    red[tid] = mx; __syncthreads();
    for (int s = 128; s > 0; s >>= 1) { if (tid < s) red[tid] = fmaxf(red[tid], red[tid + s]); __syncthreads(); }
    mx = red[0]; __syncthreads();
    float sum = 0.f;
    for (int k = tid; k < 2048; k += 256) { float e = expf(p[k] - mx); p[k] = e; sum += e; }
    red[tid] = sum; __syncthreads();
    for (int s = 128; s > 0; s >>= 1) { if (tid < s) red[tid] += red[tid + s]; __syncthreads(); }
    float inv = 1.f / red[0];
    for (int k = tid; k < 2048; k += 256) p[k] *= inv;
}

__global__ void o1_kernel(const float* __restrict__ p1, const float* __restrict__ vh,
                          float* __restrict__ Bm)
{
    int row = blockIdx.x;            // h*30+i
    int h = row / 30, i = row % 30;
    int d = threadIdx.x;             // 128
    const float* pp = p1 + row * 2048;
    const float* vp = vh + h * 2048 * 128 + d;
    float acc = 0.f;
    for (int k = 0; k < 2048; ++k) acc += pp[k] * vp[k * 128];
    Bm[i * 256 + h * 128 + d] = acc;
}

__global__ __launch_bounds__(256) void attn2_kernel(
    const float* __restrict__ qh2, const float* __restrict__ kh2, const float* __restrict__ vh2,
    const float* __restrict__ S, const float* __restrict__ Wg,
    const float* __restrict__ bg, float* __restrict__ Smix)
{
    __shared__ float ks[2 * 30 * 129];
    __shared__ float qred[256];
    __shared__ float ps[64];
    int l = blockIdx.x;
    int tid = threadIdx.x;
    for (int idx = tid; idx < 2 * 30 * 128; idx += 256) {
        int hh = idx / 3840; int rem = idx - hh * 3840;
        int j = rem >> 7; int d = rem & 127;
        ks[(hh * 30 + j) * 129 + d] = kh2[idx];
    }
    int h = tid >> 7, d = tid & 127;
    qred[tid] = qh2[(h * 2048 + l) * 128 + d];
    __syncthreads();
    int w = tid >> 6, lane = tid & 63;
    if (w < 2 && lane < 32) {
        float sc = -1e30f;
        if (lane < 30) {
            const float* qp = qred + w * 128;
            float a = 0.f;
            for (int dd = 0; dd < 128; ++dd) a += qp[dd] * ks[(w * 30 + lane) * 129 + dd];
            sc = a * 0.08838834764831845f;
        }
        float mx = sc;
        for (int m = 16; m > 0; m >>= 1) mx = fmaxf(mx, __shfl_xor(mx, m, 32));
        float e = (lane < 30) ? expf(sc - mx) : 0.f;
        float sm = e;
        for (int m = 16; m > 0; m >>= 1) sm += __shfl_xor(sm, m, 32);
        ps[w * 32 + lane] = e / sm;
    }
    __syncthreads();
    float o = 0.f;
    const float* vp = vh2 + h * 3840 + d;
    for (int j = 0; j < 30; ++j) o += ps[h * 32 + j] * vp[j * 128];
    float sl = S[l * 256 + tid];
    qred[tid] = sl * Wg[tid];
    __syncthreads();
    for (int s = 128; s > 0; s >>= 1) { if (tid < s) qred[tid] += qred[tid + s]; __syncthreads(); }
    float alpha = 1.f / (1.f + expf(-(qred[0] + bg[0])));
    Smix[l * 256 + tid] = alpha * o + (1.f - alpha) * sl;
}

__global__ void w1t_kernel(const float* __restrict__ W1, float* __restrict__ W1T)
{
    int idx = blockIdx.x * 256 + threadIdx.x;  // 65536
    int j = idx & 255, c = idx >> 8;
    W1T[j * 256 + c] = W1[c * 256 + j];
}

__global__ void mlp_kernel(const float* __restrict__ Smix, const float* __restrict__ W1T,
                           const float* __restrict__ b1, float* __restrict__ S2)
{
    int idx = blockIdx.x * 256 + threadIdx.x;  // l*256+c
    int c = idx & 255; int l = idx >> 8;
    const float* a = Smix + l * 256;
    float acc = b1[c];
    for (int j = 0; j < 256; ++j) acc += a[j] * W1T[j * 256 + c];
    float v = fmaxf(acc, 0.f);
    S2[idx] = v + a[c];
}

__global__ void y_kernel(const float* __restrict__ S2, const float* __restrict__ W2,
                         const float* __restrict__ b2, float* __restrict__ y)
{
    __shared__ float red[256];
    int l = blockIdx.x; int tid = threadIdx.x;
    red[tid] = S2[l * 256 + tid] * W2[tid];
    __syncthreads();
    for (int s = 128; s > 0; s >>= 1) { if (tid < s) red[tid] += red[tid + s]; __syncthreads(); }
    if (tid == 0) y[l] = red[0] + b2[0];
}

__global__ void norm_kernel(const float* __restrict__ y, float* __restrict__ out)
{
    __shared__ float r1[1024], r2[1024];
    int tid = threadIdx.x;
    float s1v = 0.f, s2v = 0.f;
    for (int idx = tid; idx < 2048; idx += 1024) { float v = y[idx]; s1v += v; s2v += v * v; }
    r1[tid] = s1v; r2[tid] = s2v; __syncthreads();
    for (int s = 512; s > 0; s >>= 1) {
        if (tid < s) { r1[tid] += r1[tid + s]; r2[tid] += r2[tid + s]; }
        __syncthreads();
    }
    float mean = r1[0] / 2048.f;
    float var = fmaxf((r2[0] - 2048.f * mean * mean) / 2047.f, 0.f);
    float inv = 1.f / (sqrtf(var) + 1e-8f);
    for (int idx = tid; idx < 2048; idx += 1024)
        out[idx] = (y[idx] - mean) * inv;
}

extern "C" void kernel_launch(void* const* d_in, const int* in_sizes, int n_in,
                              void* d_out, int out_size, void* d_ws, size_t ws_size,
                              hipStream_t stream)
{
    const float* x    = (const float*)d_in[0];
    const float* Wih0 = (const float*)d_in[1];
    const float* Whh0 = (const float*)d_in[2];
    const float* bih0 = (const float*)d_in[3];
    const float* bhh0 = (const float*)d_in[4];
    const float* Wih1 = (const float*)d_in[5];
    const float* Whh1 = (const float*)d_in[6];
    const float* bih1 = (const float*)d_in[7];
    const float* bhh1 = (const float*)d_in[8];
    const float* Wq   = (const float*)d_in[9];
    const float* bq   = (const float*)d_in[10];
    const float* Wk   = (const float*)d_in[11];
    const float* bk   = (const float*)d_in[12];
    const float* Wv   = (const float*)d_in[13];
    const float* bv   = (const float*)d_in[14];
    const float* R    = (const float*)d_in[15];
    const float* Wg   = (const float*)d_in[16];
    const float* bg   = (const float*)d_in[17];
    const float* W1   = (const float*)d_in[18];
    const float* b1   = (const float*)d_in[19];
    const float* W2   = (const float*)d_in[20];
    const float* b2   = (const float*)d_in[21];

    float* ws  = (float*)d_ws;
    float* H0a = ws;                       // 2048*256
    float* H0b = ws + 524288;
    float* H1a = ws + 1048576;
    float* H1b = ws + 1572864;
    float* qh2 = ws + 2097152;             // 2*2048*128
    float* qhR = ws + 2621440;             // 7680
    float* s1  = ws + 2629120;             // 122880
    float* Bm  = ws + 2752000;             // 7680
    float* kh2 = ws + 2759680;             // 7680
    float* vh2 = ws + 2767360;             // 7680
    float* Smix= ws + 2775040;             // 524288
    float* S2  = ws + 3299328;             // 524288
    float* yv  = ws + 3823616;             // 2048
    float* W1T = ws + 3825664;             // 65536
    unsigned short* wb = (unsigned short*)(ws + 3891200);
    unsigned short* Wih0hi = wb;            // 768*64
    unsigned short* Wih0lo = wb + 49152;
    unsigned short* Whh0hi = wb + 98304;    // 768*256
    unsigned short* Whh0lo = wb + 294912;
    unsigned short* Wih1hi = wb + 491520;   // 768*256
    unsigned short* Wih1lo = wb + 688128;
    unsigned short* Whh1hi = wb + 884736;   // 768*256
    unsigned short* Whh1lo = wb + 1081344;  // end 1277952 ushorts (~18.1 MB total ws use)

    // weight conversion (every call; no static state)
    cvt_hilo<<<192, 256, 0, stream>>>(Wih0, Wih0hi, Wih0lo, 49152);
    cvt_hilo<<<768, 256, 0, stream>>>(Whh0, Whh0hi, Whh0lo, 196608);
    cvt_hilo<<<768, 256, 0, stream>>>(Wih1, Wih1hi, Wih1lo, 196608);
    cvt_hilo<<<768, 256, 0, stream>>>(Whh1, Whh1hi, Whh1lo, 196608);

    // zero initial states: H0b read at i=0, H1a read at i=1
    hipMemsetAsync(H0b, 0, 524288 * sizeof(float), stream);
    hipMemsetAsync(H1a, 0, 524288 * sizeof(float), stream);

    for (int i = 0; i <= 128; ++i) {
        const float* h0r = (i & 1) ? H0a : H0b;
        float*       h0w = (i & 1) ? H0b : H0a;
        const float* h1r = (i & 1) ? H1a : H1b;
        float*       h1w = (i & 1) ? H1b : H1a;
        gru_step<<<512, 256, 0, stream>>>(h0r, h0w, h1r, h1w, x,
                                          Wih0hi, Wih0lo, Whh0hi, Whh0lo, bih0, bhh0,
                                          Wih1hi, Wih1lo, Whh1hi, Whh1lo, bih1, bhh1, i);
    }
    float* S  = H1a;   // h1 after t=127 (written at i=128, even parity -> H1a)
    float* kh = H0a;   // reuse GRU buffers as kh/vh scratch
    float* vh = H0b;

    proj3_kernel<<<6144, 256, 0, stream>>>(S, 2048, Wk, bk, Wv, bv, Wq, bq, kh, vh, qh2, 3);
    projR_kernel<<<30, 256, 0, stream>>>(R, Wq, bq, qhR);
    scores1_kernel<<<480, 256, 0, stream>>>(qhR, kh, s1);
    softmax1_kernel<<<60, 256, 0, stream>>>(s1);
    o1_kernel<<<60, 128, 0, stream>>>(s1, vh, Bm);
    proj3_kernel<<<60, 256, 0, stream>>>(Bm, 30, Wk, bk, Wv, bv, Wq, bq, kh2, vh2, (float*)0, 2);
    attn2_kernel<<<2048, 256, 0, stream>>>(qh2, kh2, vh2, S, Wg, bg, Smix);
    w1t_kernel<<<256, 256, 0, stream>>>(W1, W1T);
    mlp_kernel<<<2048, 256, 0, stream>>>(Smix, W1T, b1, S2);
    y_kernel<<<2048, 256, 0, stream>>>(S2, W2, b2, yv);
    norm_kernel<<<1, 1024, 0, stream>>>(yv, (float*)d_out);
}